// Round 6
// baseline (7786.411 us; speedup 1.0000x reference)
//
#include <hip/hip_runtime.h>

// RNNEncModel: embed -> MLP(relu x2) -> 2x bidirectional tanh-RNN -> final states [4,64,1024] f32.
// B=64 T=512 E=512 H=1024 V=32000.
// fp16 compute (f32 MFMA accum). Input projections fused into persistent scan kernels; x-tile
// register-prefetched. Round-6: barrier-release sync (ONE poller wave instead of 8), x-MFMAs
// moved BEFORE the spin (flag-independent), decoupled single-wave reduce+store+publish tail.
// h-state via LLC (sc0 sc1); monotonic flag sync. ws NEED = 196 MB.

typedef _Float16 f16;
typedef _Float16 f16x8 __attribute__((ext_vector_type(8)));
typedef _Float16 f16x4 __attribute__((ext_vector_type(4)));
typedef float f32x4 __attribute__((ext_vector_type(4)));

static const size_t MB_ = 1024ull * 1024ull;
static const size_t OFF_X0    = 0;                      // [512*64][1024] f16 = 64MB (MLP out, [t][b][h])
static const size_t OFF_X1    = 64 * MB_;               // [512*64][2048] f16 = 128MB (layer0 out)
static const size_t OFF_EMB   = OFF_X1;                 // tmp [32768][512] f16 = 32MB
static const size_t OFF_MLP1  = 96 * MB_;               // tmp [32768][1024] f16 = 64MB
static const size_t OFF_H     = 192 * MB_;              // [2dir][2buf][64][1024] f16 = 512KB
static const size_t OFF_FLAGS = 192 * MB_ + 512 * 1024; // [2dir][2bg][64cg] u32 = 1KB
static const size_t OFF_BIAS  = 192 * MB_ + 576 * 1024; // [4][1024] f32 (b_ih + b_hh)
static const size_t OFF_W1C   = 193 * MB_;              // W1 f16 [1024][512] = 1MB
static const size_t OFF_W2C   = 194 * MB_;              // W2 f16 [1024][1024] = 2MB
static const size_t WS_NEED   = 196 * MB_;

__device__ __forceinline__ void gld16(const void* g, void* l) {
#if __has_builtin(__builtin_amdgcn_global_load_lds)
  __builtin_amdgcn_global_load_lds((const __attribute__((address_space(1))) void*)g,
                                   (__attribute__((address_space(3))) void*)l, 16, 0, 0);
#else
  *(f16x8*)l = *(const f16x8*)g;
#endif
}

// fast tanh: tanh(|x|) = 1 - 2/(exp2(2*log2e*|x|)+1); hw exp + rcp, abs err ~1e-6 << f16 rounding.
__device__ __forceinline__ float tanh_fast(float x) {
  float ax = __builtin_fabsf(x);
  float e = __builtin_amdgcn_exp2f(ax * 2.8853900817779268f);
  float r = 1.0f - 2.0f * __builtin_amdgcn_rcpf(e + 1.0f);
  return __builtin_copysignf(r, x);
}

// ---------------- utility kernels ----------------

__global__ void zero_k(unsigned int* __restrict__ p, int n) {
  int i = blockIdx.x * blockDim.x + threadIdx.x;
  if (i < n) p[i] = 0u;
}

__global__ void cvt_k(const float* __restrict__ in, f16* __restrict__ out, int n4) {
  int i = blockIdx.x * blockDim.x + threadIdx.x;
  int stride = gridDim.x * blockDim.x;
  for (; i < n4; i += stride) {
    float4 v = ((const float4*)in)[i];
    f16x4 o = {(f16)v.x, (f16)v.y, (f16)v.z, (f16)v.w};
    ((f16x4*)out)[i] = o;
  }
}

__global__ void bias_k(const float* __restrict__ a, const float* __restrict__ b, float* __restrict__ o) {
  int i = blockIdx.x * blockDim.x + threadIdx.x;
  if (i < 4096) o[i] = a[i] + b[i];
}

// embedding gather + f16 convert; padding_idx=0 -> zero row
__global__ void embed_k(const int* __restrict__ src, const float* __restrict__ tab, f16* __restrict__ out) {
  int m = blockIdx.x;     // token index b*512 + t
  int tid = threadIdx.x;  // 128 threads x 4 floats
  int tok = src[m];
  f16x4 o = {(f16)0.f, (f16)0.f, (f16)0.f, (f16)0.f};
  if (tok != 0) {
    float4 v = *(const float4*)(tab + (size_t)tok * 512 + tid * 4);
    o[0] = (f16)v.x; o[1] = (f16)v.y; o[2] = (f16)v.z; o[3] = (f16)v.w;
  }
  *(f16x4*)(out + (size_t)m * 512 + tid * 4) = o;
}

// ---------------- GEMM: C[M,N] = A[M,K(lda)] * Bw[N,K]^T ----------------
// EPI bit0: relu(acc + bias[col]); EPI bit1: scatter row=(b*512+t) -> out[(t*64+b)*1024+col] (N==1024)
template <int EPI>
__global__ __launch_bounds__(256) void gemm_f16(
    const f16* __restrict__ A, int lda, const f16* __restrict__ Bw,
    f16* __restrict__ out, const float* __restrict__ bias, int M, int N, int K) {
  __shared__ alignas(16) f16 As[4096];  // [128][32]
  __shared__ alignas(16) f16 Bs[4096];  // [128][32]
  const int nt = N >> 7;
  const int bx = blockIdx.x;
  const int tm = bx / nt, tn = bx - tm * nt;
  const int tid = threadIdx.x;
  const int l = tid & 63, w = tid >> 6;
  const int wr = w >> 1, wc = w & 1;
  const int srow = (w << 4) + (l >> 2);
  const int scol = (l & 3) << 3;
  const f16* Ab = A + (size_t)(tm * 128 + srow) * lda + scol;
  const f16* Bb = Bw + (size_t)(tn * 128 + srow) * K + scol;
  f32x4 acc[4][4];
#pragma unroll
  for (int i = 0; i < 4; i++)
#pragma unroll
    for (int j = 0; j < 4; j++) acc[i][j] = (f32x4){0.f, 0.f, 0.f, 0.f};
  const int ar = l & 15, ak = (l >> 4) << 3;
  for (int k0 = 0; k0 < K; k0 += 32) {
    gld16(Ab + k0, &As[tid * 8]);
    gld16(Ab + (size_t)64 * lda + k0, &As[tid * 8 + 2048]);
    gld16(Bb + k0, &Bs[tid * 8]);
    gld16(Bb + (size_t)64 * K + k0, &Bs[tid * 8 + 2048]);
    __syncthreads();
    f16x8 av[4], bv[4];
#pragma unroll
    for (int i = 0; i < 4; i++) av[i] = *(const f16x8*)&As[(wr * 64 + i * 16 + ar) * 32 + ak];
#pragma unroll
    for (int j = 0; j < 4; j++) bv[j] = *(const f16x8*)&Bs[(wc * 64 + j * 16 + ar) * 32 + ak];
#pragma unroll
    for (int i = 0; i < 4; i++)
#pragma unroll
      for (int j = 0; j < 4; j++)
        acc[i][j] = __builtin_amdgcn_mfma_f32_16x16x32_f16(av[i], bv[j], acc[i][j], 0, 0, 0);
    __syncthreads();
  }
  const int r0 = (l >> 4) << 2, c0 = l & 15;
#pragma unroll
  for (int i = 0; i < 4; i++) {
#pragma unroll
    for (int j = 0; j < 4; j++) {
      const int col = tn * 128 + wc * 64 + j * 16 + c0;
      const float bc = (EPI & 1) ? bias[col] : 0.f;
#pragma unroll
      for (int r = 0; r < 4; r++) {
        const int row = tm * 128 + wr * 64 + i * 16 + r0 + r;
        float v = acc[i][j][r];
        if (EPI & 1) { v += bc; v = v > 0.f ? v : 0.f; }
        if (EPI & 2) {
          const int b_ = row >> 9, t = row & 511;
          out[((size_t)(t * 64 + b_) << 10) + col] = (f16)v;
        } else {
          out[(size_t)row * N + col] = (f16)v;
        }
      }
    }
  }
}

// ---------------- fused recurrence ----------------
// grid 256 = dir(2) x bg(2, 32 batch rows) x cg(64, 16 cols). Block 512 thr = 8 waves:
// (mi batch-half, kq K-quarter). Per step: h_new = tanh(x[t]@Wih^T + h@Whh^T + bias).
// Schedule per step (barrier-release sync):
//   vmcnt(0) [x regs ready] -> x MFMAs (flag-independent, pre-spin)
//   wave7 polls 64 group flags; __syncthreads releases all
//   all waves: 8 h LLC-loads (sc0 sc1) -> vmcnt(0) -> h MFMAs -> part[mi][kq] LDS
//   __syncthreads
//   wave0 alone: reduce both mi, +bias, tanh, p2 LDS bounce -> coalesced dwordx4 h+seq stores
//                -> vmcnt(0) -> publish flag   (NO trailing barrier: others already issue next x)
// part WAR across steps is safe: next-iteration first barrier requires wave0.
template <int LAYER>
__global__ __launch_bounds__(512, 1) void rnn_scan(
    const f16* __restrict__ X,       // [512*64][KX]  (t-major)
    const float* __restrict__ Wih,   // [2][1024][KX] f32
    const float* __restrict__ Whh,   // [2][2][1024][1024] f32
    const float* __restrict__ bsum,  // [4][1024]
    f16* __restrict__ hbuf,          // [2][2][64][1024] f16
    unsigned int* __restrict__ flags,// [2][2][64] u32
    f16* __restrict__ seqout,        // LAYER0: [512*64][2048]
    float* __restrict__ dout) {      // [4][64][1024]
  constexpr int KX = LAYER ? 2048 : 1024;
  constexpr int XSH = LAYER ? 11 : 10;
  constexpr int NKX = KX / 128;  // x k-steps per wave (8 or 16)
  constexpr int NKH = 8;         // h k-steps per wave (1024/4/32)
  const int bid = blockIdx.x;
  const int dir = bid >> 7, bg = (bid >> 6) & 1, cg = bid & 63;
  const int tid = threadIdx.x, l = tid & 63, w = tid >> 6;
  const int mi = w & 1, kq = w >> 1;
  __shared__ alignas(16) f16 Wl[16 * 1024];   // Whh slice, 32KB
  __shared__ alignas(16) f16 Wi[16 * KX];     // Wih slice, 32/64KB
  __shared__ f32x4 part[2][4][64];            // K-quarter partials, 8KB
  __shared__ alignas(16) f16 p2[32][16];      // tanh results for batched store, 1KB
  const int ld = LAYER * 2 + dir;
  // stage Whh slice (16 out-cols x 1024) f32 -> f16, XOR swizzle (k0 ^= (n&7)<<3)
  for (int ch = tid; ch < 2048; ch += 512) {
    const int n = ch >> 7, k0 = (ch & 127) << 3;
    const float* wp = Whh + (((size_t)(ld * 1024 + cg * 16 + n)) << 10) + k0;
    float4 v0 = *(const float4*)wp, v1 = *(const float4*)(wp + 4);
    f16x8 hv = {(f16)v0.x, (f16)v0.y, (f16)v0.z, (f16)v0.w,
                (f16)v1.x, (f16)v1.y, (f16)v1.z, (f16)v1.w};
    *(f16x8*)&Wl[(n << 10) + (k0 ^ ((n & 7) << 3))] = hv;
  }
  // stage Wih slice (16 out-cols x KX) f32 -> f16, same swizzle
  for (int ch = tid; ch < (16 * KX / 8); ch += 512) {
    const int n = ch >> (XSH - 3), k0 = (ch & (KX / 8 - 1)) << 3;
    const float* wp = Wih + ((size_t)(dir * 1024 + cg * 16 + n)) * KX + k0;
    float4 v0 = *(const float4*)wp, v1 = *(const float4*)(wp + 4);
    f16x8 hv = {(f16)v0.x, (f16)v0.y, (f16)v0.z, (f16)v0.w,
                (f16)v1.x, (f16)v1.y, (f16)v1.z, (f16)v1.w};
    *(f16x8*)&Wi[(n << XSH) + (k0 ^ ((n & 7) << 3))] = hv;
  }
  const float bn = bsum[(ld << 10) + cg * 16 + (l & 15)];
  f16* hD = hbuf + ((size_t)dir << 17);
  unsigned int* fl = flags + ((dir * 2 + bg) << 6);
  const int arow = bg * 32 + mi * 16 + (l & 15);      // batch row (MFMA M-dim)
  const int akh = (kq << 8) + ((l >> 4) << 3);        // Whh k-offset of this lane's fragment
  const int akx = kq * (KX / 4) + ((l >> 4) << 3);    // Wih k-offset
  const int wn = l & 15;
  const int wsw = (wn & 7) << 3;

  f16x8 xv[NKX];
  {  // prologue: issue x loads for s=0
    const int t0 = dir ? 511 : 0;
    const f16* xr = X + (((size_t)(t0 * 64 + arow)) << XSH) + akx;
#pragma unroll
    for (int i = 0; i < NKX; i++)
      asm volatile("global_load_dwordx4 %0, %1, off offset:%2"
                   : "=&v"(xv[i]) : "v"(xr), "i"(64 * i));
  }
  __syncthreads();  // staging complete

  for (int s = 0; s < 512; ++s) {
    const int t = dir ? (511 - s) : s;
    // ---- x projection: needs only regs + LDS; runs BEFORE the flag wait ----
    asm volatile("s_waitcnt vmcnt(0)" ::: "memory");  // xv ready (only x loads outstanding)
    __builtin_amdgcn_sched_barrier(0);
    f32x4 acc = {0.f, 0.f, 0.f, 0.f};
#pragma unroll
    for (int it = 0; it < NKX; ++it) {
      const int ko = akx + it * 32;
      f16x8 bv = *(const f16x8*)&Wi[(wn << XSH) + (ko ^ wsw)];
      acc = __builtin_amdgcn_mfma_f32_16x16x32_f16(xv[it], bv, acc, 0, 0, 0);
    }
    // ---- barrier-release flag wait: one wave polls, barrier releases the rest ----
    if (s > 0 && w == 7) {
      const unsigned int tgt = (unsigned int)(LAYER * 512 + s);
      unsigned int* fp = fl + l;  // lane <-> cg flag
      for (;;) {
        unsigned int f = __hip_atomic_load(fp, __ATOMIC_RELAXED, __HIP_MEMORY_SCOPE_AGENT);
        if (__all((int)(f >= tgt))) break;
      }
    }
    __syncthreads();
    if (s > 0) {
      // h: 8 LLC loads (sc0 sc1), drain, MFMA
      const f16* hrow = hD + (((size_t)(s & 1)) << 16) + (((size_t)arow) << 10) + akh;
      f16x8 hv[NKH];
#pragma unroll
      for (int i = 0; i < NKH; i++)
        asm volatile("global_load_dwordx4 %0, %1, off offset:%2 sc0 sc1"
                     : "=&v"(hv[i]) : "v"(hrow), "i"(64 * i));
      asm volatile("s_waitcnt vmcnt(0)" ::: "memory");
      __builtin_amdgcn_sched_barrier(0);
#pragma unroll
      for (int it = 0; it < NKH; ++it) {
        const int ko = akh + it * 32;
        f16x8 bv = *(const f16x8*)&Wl[(wn << 10) + (ko ^ wsw)];
        acc = __builtin_amdgcn_mfma_f32_16x16x32_f16(hv[it], bv, acc, 0, 0, 0);
      }
    }
    part[mi][kq][l] = acc;  // linear b128, conflict-free
    __syncthreads();
    // ---- single-wave tail: reduce, tanh, store, publish (others run ahead) ----
    if (w == 0) {
#pragma unroll
      for (int m = 0; m < 2; ++m) {
        f32x4 sum = part[m][0][l];
        sum += part[m][1][l];
        sum += part[m][2][l];
        sum += part[m][3][l];
#pragma unroll
        for (int r = 0; r < 4; ++r) {
          const int row = ((l >> 4) << 2) + r;
          float v = tanh_fast(sum[r] + bn);
          p2[(m << 4) + row][l & 15] = (f16)v;
          if (s == 511) {
            const int b_ = bg * 32 + (m << 4) + row;
            dout[(((size_t)(ld * 64 + b_)) << 10) + cg * 16 + (l & 15)] = v;
          }
        }
      }
      asm volatile("s_waitcnt lgkmcnt(0)" ::: "memory");  // p2 visible across lanes (same wave)
      const int rr = l >> 1, hf = l & 1;
      f16x8 pv = *(const f16x8*)&p2[rr][hf * 8];
      const int b_ = bg * 32 + rr;
      f16* hp = hD + (((size_t)((s + 1) & 1)) << 16) + (((size_t)b_) << 10) + cg * 16 + hf * 8;
      asm volatile("global_store_dwordx4 %0, %1, off sc0 sc1" :: "v"(hp), "v"(pv) : "memory");
      if (LAYER == 0) {
        f16* sp = seqout + (((size_t)(t * 64 + b_)) << 11) + (dir << 10) + cg * 16 + hf * 8;
        asm volatile("global_store_dwordx4 %0, %1, off" :: "v"(sp), "v"(pv) : "memory");
      }
      asm volatile("s_waitcnt vmcnt(0)" ::: "memory");  // h stores globally visible
      if (l == 0)
        __hip_atomic_store(&fl[cg], (unsigned int)(LAYER * 512 + s + 1),
                           __ATOMIC_RELAXED, __HIP_MEMORY_SCOPE_AGENT);
    }
    // ---- issue x loads for next step (hides under next spin) ----
    if (s + 1 < 512) {
      const int tn_ = dir ? (511 - (s + 1)) : (s + 1);
      const f16* xr = X + (((size_t)(tn_ * 64 + arow)) << XSH) + akx;
#pragma unroll
      for (int i = 0; i < NKX; i++)
        asm volatile("global_load_dwordx4 %0, %1, off offset:%2"
                     : "=&v"(xv[i]) : "v"(xr), "i"(64 * i));
    }
  }
}

// ---------------- launch ----------------

extern "C" void kernel_launch(void* const* d_in, const int* in_sizes, int n_in,
                              void* d_out, int out_size, void* d_ws, size_t ws_size,
                              hipStream_t stream) {
  const int* src    = (const int*)d_in[0];
  const float* emb  = (const float*)d_in[1];
  const float* W1   = (const float*)d_in[2];
  const float* b1   = (const float*)d_in[3];
  const float* W2   = (const float*)d_in[4];
  const float* b2   = (const float*)d_in[5];
  const float* Wih0 = (const float*)d_in[6];
  const float* WihL = (const float*)d_in[7];
  const float* Whh  = (const float*)d_in[8];
  const float* bih  = (const float*)d_in[9];
  const float* bhh  = (const float*)d_in[10];
  float* out = (float*)d_out;
  char* ws = (char*)d_ws;

  if (ws_size < WS_NEED) {  // diagnostic fallback: clean absmax-fail instead of OOB fault
    zero_k<<<(out_size + 255) / 256, 256, 0, stream>>>((unsigned int*)d_out, out_size);
    return;
  }

  f16* X0   = (f16*)(ws + OFF_X0);
  f16* X1   = (f16*)(ws + OFF_X1);
  f16* EMB  = (f16*)(ws + OFF_EMB);
  f16* MLP1 = (f16*)(ws + OFF_MLP1);
  f16* HB   = (f16*)(ws + OFF_H);
  unsigned int* FLAGS = (unsigned int*)(ws + OFF_FLAGS);
  float* BIAS = (float*)(ws + OFF_BIAS);
  f16* W1C  = (f16*)(ws + OFF_W1C);
  f16* W2C  = (f16*)(ws + OFF_W2C);

  cvt_k<<<256, 256, 0, stream>>>(W1, W1C, 131072);
  cvt_k<<<256, 256, 0, stream>>>(W2, W2C, 262144);
  bias_k<<<16, 256, 0, stream>>>(bih, bhh, BIAS);
  zero_k<<<1, 256, 0, stream>>>(FLAGS, 256);

  embed_k<<<32768, 128, 0, stream>>>(src, emb, EMB);
  gemm_f16<1><<<2048, 256, 0, stream>>>(EMB, 512, W1C, MLP1, b1, 32768, 1024, 512);
  gemm_f16<3><<<2048, 256, 0, stream>>>(MLP1, 1024, W2C, X0, b2, 32768, 1024, 1024);

  rnn_scan<0><<<256, 512, 0, stream>>>(X0, Wih0, Whh, BIAS, HB, FLAGS, X1, out);
  rnn_scan<1><<<256, 512, 0, stream>>>(X1, WihL, Whh, BIAS, HB, FLAGS, nullptr, out);
}

// Round 8
// 5902.173 us; speedup vs baseline: 1.3192x; 1.3192x over previous
//
#include <hip/hip_runtime.h>

// RNNEncModel: embed -> MLP(relu x2) -> 2x bidirectional tanh-RNN -> final states [4,64,1024] f32.
// B=64 T=512 E=512 H=1024 V=32000.
// fp16 compute (f32 MFMA accum). Round-8: R5 ordering (poll -> h-issue -> vmcnt(NKH) -> x-MFMA ->
// vmcnt(0) -> h-MFMA) + single-poller barrier release + two-wave tail + LDS-atomic last-man
// publish + padded flags. ONE common bottom next-x issue site (divergent issue sites in R7
// produced phi copies of in-flight load dests -> NaN). ws NEED = 196 MB.

typedef _Float16 f16;
typedef _Float16 f16x8 __attribute__((ext_vector_type(8)));
typedef _Float16 f16x4 __attribute__((ext_vector_type(4)));
typedef float f32x4 __attribute__((ext_vector_type(4)));

static const size_t MB_ = 1024ull * 1024ull;
static const size_t OFF_X0    = 0;                      // [512*64][1024] f16 = 64MB (MLP out, [t][b][h])
static const size_t OFF_X1    = 64 * MB_;               // [512*64][2048] f16 = 128MB (layer0 out)
static const size_t OFF_EMB   = OFF_X1;                 // tmp [32768][512] f16 = 32MB
static const size_t OFF_MLP1  = 96 * MB_;               // tmp [32768][1024] f16 = 64MB
static const size_t OFF_H     = 192 * MB_;              // [2dir][2buf][64][1024] f16 = 512KB
static const size_t OFF_FLAGS = 192 * MB_ + 512 * 1024; // [2dir][2bg][64cg][16] u32 = 16KB (64B pad)
static const size_t OFF_BIAS  = 192 * MB_ + 576 * 1024; // [4][1024] f32 (b_ih + b_hh)
static const size_t OFF_W1C   = 193 * MB_;              // W1 f16 [1024][512] = 1MB
static const size_t OFF_W2C   = 194 * MB_;              // W2 f16 [1024][1024] = 2MB
static const size_t WS_NEED   = 196 * MB_;

__device__ __forceinline__ void gld16(const void* g, void* l) {
#if __has_builtin(__builtin_amdgcn_global_load_lds)
  __builtin_amdgcn_global_load_lds((const __attribute__((address_space(1))) void*)g,
                                   (__attribute__((address_space(3))) void*)l, 16, 0, 0);
#else
  *(f16x8*)l = *(const f16x8*)g;
#endif
}

// fast tanh: tanh(|x|) = 1 - 2/(exp2(2*log2e*|x|)+1); hw exp + rcp, abs err ~1e-6 << f16 rounding.
__device__ __forceinline__ float tanh_fast(float x) {
  float ax = __builtin_fabsf(x);
  float e = __builtin_amdgcn_exp2f(ax * 2.8853900817779268f);
  float r = 1.0f - 2.0f * __builtin_amdgcn_rcpf(e + 1.0f);
  return __builtin_copysignf(r, x);
}

// ---------------- utility kernels ----------------

__global__ void zero_k(unsigned int* __restrict__ p, int n) {
  int i = blockIdx.x * blockDim.x + threadIdx.x;
  if (i < n) p[i] = 0u;
}

__global__ void cvt_k(const float* __restrict__ in, f16* __restrict__ out, int n4) {
  int i = blockIdx.x * blockDim.x + threadIdx.x;
  int stride = gridDim.x * blockDim.x;
  for (; i < n4; i += stride) {
    float4 v = ((const float4*)in)[i];
    f16x4 o = {(f16)v.x, (f16)v.y, (f16)v.z, (f16)v.w};
    ((f16x4*)out)[i] = o;
  }
}

__global__ void bias_k(const float* __restrict__ a, const float* __restrict__ b, float* __restrict__ o) {
  int i = blockIdx.x * blockDim.x + threadIdx.x;
  if (i < 4096) o[i] = a[i] + b[i];
}

// embedding gather + f16 convert; padding_idx=0 -> zero row
__global__ void embed_k(const int* __restrict__ src, const float* __restrict__ tab, f16* __restrict__ out) {
  int m = blockIdx.x;     // token index b*512 + t
  int tid = threadIdx.x;  // 128 threads x 4 floats
  int tok = src[m];
  f16x4 o = {(f16)0.f, (f16)0.f, (f16)0.f, (f16)0.f};
  if (tok != 0) {
    float4 v = *(const float4*)(tab + (size_t)tok * 512 + tid * 4);
    o[0] = (f16)v.x; o[1] = (f16)v.y; o[2] = (f16)v.z; o[3] = (f16)v.w;
  }
  *(f16x4*)(out + (size_t)m * 512 + tid * 4) = o;
}

// ---------------- GEMM: C[M,N] = A[M,K(lda)] * Bw[N,K]^T ----------------
// EPI bit0: relu(acc + bias[col]); EPI bit1: scatter row=(b*512+t) -> out[(t*64+b)*1024+col] (N==1024)
template <int EPI>
__global__ __launch_bounds__(256) void gemm_f16(
    const f16* __restrict__ A, int lda, const f16* __restrict__ Bw,
    f16* __restrict__ out, const float* __restrict__ bias, int M, int N, int K) {
  __shared__ alignas(16) f16 As[4096];  // [128][32]
  __shared__ alignas(16) f16 Bs[4096];  // [128][32]
  const int nt = N >> 7;
  const int bx = blockIdx.x;
  const int tm = bx / nt, tn = bx - tm * nt;
  const int tid = threadIdx.x;
  const int l = tid & 63, w = tid >> 6;
  const int wr = w >> 1, wc = w & 1;
  const int srow = (w << 4) + (l >> 2);
  const int scol = (l & 3) << 3;
  const f16* Ab = A + (size_t)(tm * 128 + srow) * lda + scol;
  const f16* Bb = Bw + (size_t)(tn * 128 + srow) * K + scol;
  f32x4 acc[4][4];
#pragma unroll
  for (int i = 0; i < 4; i++)
#pragma unroll
    for (int j = 0; j < 4; j++) acc[i][j] = (f32x4){0.f, 0.f, 0.f, 0.f};
  const int ar = l & 15, ak = (l >> 4) << 3;
  for (int k0 = 0; k0 < K; k0 += 32) {
    gld16(Ab + k0, &As[tid * 8]);
    gld16(Ab + (size_t)64 * lda + k0, &As[tid * 8 + 2048]);
    gld16(Bb + k0, &Bs[tid * 8]);
    gld16(Bb + (size_t)64 * K + k0, &Bs[tid * 8 + 2048]);
    __syncthreads();
    f16x8 av[4], bv[4];
#pragma unroll
    for (int i = 0; i < 4; i++) av[i] = *(const f16x8*)&As[(wr * 64 + i * 16 + ar) * 32 + ak];
#pragma unroll
    for (int j = 0; j < 4; j++) bv[j] = *(const f16x8*)&Bs[(wc * 64 + j * 16 + ar) * 32 + ak];
#pragma unroll
    for (int i = 0; i < 4; i++)
#pragma unroll
      for (int j = 0; j < 4; j++)
        acc[i][j] = __builtin_amdgcn_mfma_f32_16x16x32_f16(av[i], bv[j], acc[i][j], 0, 0, 0);
    __syncthreads();
  }
  const int r0 = (l >> 4) << 2, c0 = l & 15;
#pragma unroll
  for (int i = 0; i < 4; i++) {
#pragma unroll
    for (int j = 0; j < 4; j++) {
      const int col = tn * 128 + wc * 64 + j * 16 + c0;
      const float bc = (EPI & 1) ? bias[col] : 0.f;
#pragma unroll
      for (int r = 0; r < 4; r++) {
        const int row = tm * 128 + wr * 64 + i * 16 + r0 + r;
        float v = acc[i][j][r];
        if (EPI & 1) { v += bc; v = v > 0.f ? v : 0.f; }
        if (EPI & 2) {
          const int b_ = row >> 9, t = row & 511;
          out[((size_t)(t * 64 + b_) << 10) + col] = (f16)v;
        } else {
          out[(size_t)row * N + col] = (f16)v;
        }
      }
    }
  }
}

// ---------------- fused recurrence ----------------
// grid 256 = dir(2) x bg(2, 32 batch rows) x cg(64, 16 cols). Block 512 thr = 8 waves:
// (mi batch-half, kq K-quarter). Per step: h_new = tanh(x[t]@Wih^T + h@Whh^T + bias).
// Step schedule (R5 ordering + single poller + decoupled two-wave tail):
//   s>0: w7 polls padded flags; s_barrier releases block
//        issue 8 h LLC-loads -> vmcnt(8) [x drained] -> x MFMAs (h in flight)
//        -> vmcnt(0) -> h MFMAs
//   s=0: vmcnt(0) -> x MFMAs
//   part[mi][kq] -> s_barrier
//   w0/w1 (half mi==w): 4-way K-reduce + bias + tanh -> p2 -> lgkm -> coalesced h(+seq) stores
//        -> vmcnt(0) -> l0: LDS-atomic inc; second arriver publishes flag. No trailing barrier.
//   ALL waves: single common bottom site issues next-x (phi-safe; divergent sites NaN'd in R7).
template <int LAYER>
__global__ __launch_bounds__(512, 1) void rnn_scan(
    const f16* __restrict__ X,       // [512*64][KX]  (t-major)
    const float* __restrict__ Wih,   // [2][1024][KX] f32
    const float* __restrict__ Whh,   // [2][2][1024][1024] f32
    const float* __restrict__ bsum,  // [4][1024]
    f16* __restrict__ hbuf,          // [2][2][64][1024] f16
    unsigned int* __restrict__ flags,// [2][2][64][16] u32 (64B padded per cg)
    f16* __restrict__ seqout,        // LAYER0: [512*64][2048]
    float* __restrict__ dout) {      // [4][64][1024]
  constexpr int KX = LAYER ? 2048 : 1024;
  constexpr int XSH = LAYER ? 11 : 10;
  constexpr int NKX = KX / 128;  // x k-steps / prefetch regs per wave (8 or 16)
  constexpr int NKH = 8;         // h k-steps per wave
  const int bid = blockIdx.x;
  const int dir = bid >> 7, bg = (bid >> 6) & 1, cg = bid & 63;
  const int tid = threadIdx.x, l = tid & 63, w = tid >> 6;
  const int mi = w & 1, kq = w >> 1;
  __shared__ alignas(16) f16 Wl[16 * 1024];   // Whh slice, 32KB
  __shared__ alignas(16) f16 Wi[16 * KX];     // Wih slice, 32/64KB
  __shared__ f32x4 part[2][4][64];            // K-quarter partials, 8KB
  __shared__ alignas(16) f16 p2[32][16];      // tanh results for batched store, 1KB
  __shared__ unsigned int cnt;                // monotonic publish counter
  const int ld = LAYER * 2 + dir;
  if (tid == 0) cnt = 0u;
  // stage Whh slice (16 out-cols x 1024) f32 -> f16, XOR swizzle (k0 ^= (n&7)<<3)
  for (int ch = tid; ch < 2048; ch += 512) {
    const int n = ch >> 7, k0 = (ch & 127) << 3;
    const float* wp = Whh + (((size_t)(ld * 1024 + cg * 16 + n)) << 10) + k0;
    float4 v0 = *(const float4*)wp, v1 = *(const float4*)(wp + 4);
    f16x8 hv = {(f16)v0.x, (f16)v0.y, (f16)v0.z, (f16)v0.w,
                (f16)v1.x, (f16)v1.y, (f16)v1.z, (f16)v1.w};
    *(f16x8*)&Wl[(n << 10) + (k0 ^ ((n & 7) << 3))] = hv;
  }
  // stage Wih slice (16 out-cols x KX) f32 -> f16, same swizzle
  for (int ch = tid; ch < (16 * KX / 8); ch += 512) {
    const int n = ch >> (XSH - 3), k0 = (ch & (KX / 8 - 1)) << 3;
    const float* wp = Wih + ((size_t)(dir * 1024 + cg * 16 + n)) * KX + k0;
    float4 v0 = *(const float4*)wp, v1 = *(const float4*)(wp + 4);
    f16x8 hv = {(f16)v0.x, (f16)v0.y, (f16)v0.z, (f16)v0.w,
                (f16)v1.x, (f16)v1.y, (f16)v1.z, (f16)v1.w};
    *(f16x8*)&Wi[(n << XSH) + (k0 ^ ((n & 7) << 3))] = hv;
  }
  const float bn = bsum[(ld << 10) + cg * 16 + (l & 15)];
  f16* hD = hbuf + ((size_t)dir << 17);
  unsigned int* fl = flags + ((dir * 2 + bg) << 10);   // 64 cg x 16 u32
  const int arow = bg * 32 + mi * 16 + (l & 15);       // batch row (MFMA M-dim)
  const int akh = (kq << 8) + ((l >> 4) << 3);         // Whh k-offset of this lane's fragment
  const int akx = kq * (KX / 4) + ((l >> 4) << 3);     // Wih k-offset
  const int wn = l & 15;
  const int wsw = (wn & 7) << 3;

  f16x8 xv[NKX];
  {  // prologue: issue x loads for s=0
    const int t0 = dir ? 511 : 0;
    const f16* xr = X + (((size_t)(t0 * 64 + arow)) << XSH) + akx;
#pragma unroll
    for (int i = 0; i < NKX; i++)
      asm volatile("global_load_dwordx4 %0, %1, off offset:%2"
                   : "=&v"(xv[i]) : "v"(xr), "i"(64 * i));
  }
  __syncthreads();  // staging + cnt init complete

  for (int s = 0; s < 512; ++s) {
    const int t = dir ? (511 - s) : s;
    f32x4 acc = {0.f, 0.f, 0.f, 0.f};
    if (s > 0) {
      // ---- single poller, barrier release ----
      if (w == 7) {
        const unsigned int tgt = (unsigned int)(LAYER * 512 + s);
        unsigned int* fp = fl + l * 16;  // lane <-> cg flag (64B stride)
        for (;;) {
          unsigned int f = __hip_atomic_load(fp, __ATOMIC_RELAXED, __HIP_MEMORY_SCOPE_AGENT);
          if (__all((int)(f >= tgt))) break;
        }
      }
      __syncthreads();
      // ---- h: issue 8 LLC loads; x loads (older) drain via vmcnt(8) ----
      const f16* hrow = hD + (((size_t)(s & 1)) << 16) + (((size_t)arow) << 10) + akh;
      f16x8 hv[NKH];
#pragma unroll
      for (int i = 0; i < NKH; i++)
        asm volatile("global_load_dwordx4 %0, %1, off offset:%2 sc0 sc1"
                     : "=&v"(hv[i]) : "v"(hrow), "i"(64 * i));
      asm volatile("s_waitcnt vmcnt(%0)" :: "i"(NKH) : "memory");
      __builtin_amdgcn_sched_barrier(0);
#pragma unroll
      for (int it = 0; it < NKX; ++it) {  // x @ Wih^T (h loads in flight underneath)
        const int ko = akx + it * 32;
        f16x8 bv = *(const f16x8*)&Wi[(wn << XSH) + (ko ^ wsw)];
        acc = __builtin_amdgcn_mfma_f32_16x16x32_f16(xv[it], bv, acc, 0, 0, 0);
      }
      asm volatile("s_waitcnt vmcnt(0)" ::: "memory");
      __builtin_amdgcn_sched_barrier(0);
#pragma unroll
      for (int it = 0; it < NKH; ++it) {  // h @ Whh^T
        const int ko = akh + it * 32;
        f16x8 bv = *(const f16x8*)&Wl[(wn << 10) + (ko ^ wsw)];
        acc = __builtin_amdgcn_mfma_f32_16x16x32_f16(hv[it], bv, acc, 0, 0, 0);
      }
    } else {
      asm volatile("s_waitcnt vmcnt(0)" ::: "memory");
      __builtin_amdgcn_sched_barrier(0);
#pragma unroll
      for (int it = 0; it < NKX; ++it) {
        const int ko = akx + it * 32;
        f16x8 bv = *(const f16x8*)&Wi[(wn << XSH) + (ko ^ wsw)];
        acc = __builtin_amdgcn_mfma_f32_16x16x32_f16(xv[it], bv, acc, 0, 0, 0);
      }
    }
    part[mi][kq][l] = acc;  // linear b128, conflict-free
    __syncthreads();
    if (w < 2) {
      // ---- reducer wave w handles batch-half mi==w ----
      f32x4 sum = part[w][0][l];
      sum += part[w][1][l];
      sum += part[w][2][l];
      sum += part[w][3][l];
#pragma unroll
      for (int r = 0; r < 4; ++r) {
        const int row = ((l >> 4) << 2) + r;
        float v = tanh_fast(sum[r] + bn);
        p2[(w << 4) + row][l & 15] = (f16)v;
        if (s == 511) {
          const int b_ = bg * 32 + (w << 4) + row;
          dout[(((size_t)(ld * 64 + b_)) << 10) + cg * 16 + (l & 15)] = v;
        }
      }
      asm volatile("s_waitcnt lgkmcnt(0)" ::: "memory");  // p2 cross-lane visible
      __builtin_amdgcn_sched_barrier(0);
      if (l < 32) {  // this wave's 16 rows x 32B -> 32 dwordx4 stores
        const int rr = (w << 4) + (l >> 1), hf = l & 1;
        f16x8 pv = *(const f16x8*)&p2[rr][hf * 8];
        const int b_ = bg * 32 + rr;
        f16* hp = hD + (((size_t)((s + 1) & 1)) << 16) + (((size_t)b_) << 10) + cg * 16 + hf * 8;
        asm volatile("global_store_dwordx4 %0, %1, off sc0 sc1" :: "v"(hp), "v"(pv) : "memory");
        if (LAYER == 0) {
          f16* sp = seqout + (((size_t)(t * 64 + b_)) << 11) + (dir << 10) + cg * 16 + hf * 8;
          asm volatile("global_store_dwordx4 %0, %1, off" :: "v"(sp), "v"(pv) : "memory");
        }
      }
      asm volatile("s_waitcnt vmcnt(0)" ::: "memory");  // stores visible at LLC
      __builtin_amdgcn_sched_barrier(0);
      if (l == 0) {  // last-man-out publishes (two incs per step: olds 2s, 2s+1)
        unsigned int old = __hip_atomic_fetch_add(&cnt, 1u, __ATOMIC_RELAXED,
                                                  __HIP_MEMORY_SCOPE_WORKGROUP);
        if (old == (unsigned int)(2 * s + 1))
          __hip_atomic_store(&fl[cg * 16], (unsigned int)(LAYER * 512 + s + 1),
                             __ATOMIC_RELAXED, __HIP_MEMORY_SCOPE_AGENT);
      }
    }
    // ---- SINGLE common issue site: next-step x loads (all waves) ----
    if (s + 1 < 512) {
      const int tn_ = dir ? (511 - (s + 1)) : (s + 1);
      const f16* xr = X + (((size_t)(tn_ * 64 + arow)) << XSH) + akx;
#pragma unroll
      for (int i = 0; i < NKX; i++)
        asm volatile("global_load_dwordx4 %0, %1, off offset:%2"
                     : "=&v"(xv[i]) : "v"(xr), "i"(64 * i));
    }
  }
}

// ---------------- launch ----------------

extern "C" void kernel_launch(void* const* d_in, const int* in_sizes, int n_in,
                              void* d_out, int out_size, void* d_ws, size_t ws_size,
                              hipStream_t stream) {
  const int* src    = (const int*)d_in[0];
  const float* emb  = (const float*)d_in[1];
  const float* W1   = (const float*)d_in[2];
  const float* b1   = (const float*)d_in[3];
  const float* W2   = (const float*)d_in[4];
  const float* b2   = (const float*)d_in[5];
  const float* Wih0 = (const float*)d_in[6];
  const float* WihL = (const float*)d_in[7];
  const float* Whh  = (const float*)d_in[8];
  const float* bih  = (const float*)d_in[9];
  const float* bhh  = (const float*)d_in[10];
  float* out = (float*)d_out;
  char* ws = (char*)d_ws;

  if (ws_size < WS_NEED) {  // diagnostic fallback: clean absmax-fail instead of OOB fault
    zero_k<<<(out_size + 255) / 256, 256, 0, stream>>>((unsigned int*)d_out, out_size);
    return;
  }

  f16* X0   = (f16*)(ws + OFF_X0);
  f16* X1   = (f16*)(ws + OFF_X1);
  f16* EMB  = (f16*)(ws + OFF_EMB);
  f16* MLP1 = (f16*)(ws + OFF_MLP1);
  f16* HB   = (f16*)(ws + OFF_H);
  unsigned int* FLAGS = (unsigned int*)(ws + OFF_FLAGS);
  float* BIAS = (float*)(ws + OFF_BIAS);
  f16* W1C  = (f16*)(ws + OFF_W1C);
  f16* W2C  = (f16*)(ws + OFF_W2C);

  cvt_k<<<256, 256, 0, stream>>>(W1, W1C, 131072);
  cvt_k<<<256, 256, 0, stream>>>(W2, W2C, 262144);
  bias_k<<<16, 256, 0, stream>>>(bih, bhh, BIAS);
  zero_k<<<16, 256, 0, stream>>>(FLAGS, 4096);

  embed_k<<<32768, 128, 0, stream>>>(src, emb, EMB);
  gemm_f16<1><<<2048, 256, 0, stream>>>(EMB, 512, W1C, MLP1, b1, 32768, 1024, 512);
  gemm_f16<3><<<2048, 256, 0, stream>>>(MLP1, 1024, W2C, X0, b2, 32768, 1024, 1024);

  rnn_scan<0><<<256, 512, 0, stream>>>(X0, Wih0, Whh, BIAS, HB, FLAGS, X1, out);
  rnn_scan<1><<<256, 512, 0, stream>>>(X1, WihL, Whh, BIAS, HB, FLAGS, nullptr, out);
}

// Round 9
// 5898.131 us; speedup vs baseline: 1.3201x; 1.0007x over previous
//
#include <hip/hip_runtime.h>

// RNNEncModel: embed -> MLP(relu x2) -> 2x bidirectional tanh-RNN -> final states [4,64,1024] f32.
// B=64 T=512 E=512 H=1024 V=32000.
// Round-9 dual path:
//  - ws >= 272MB: PRE path — input projections precomputed as GEMMs; scans read a 2KB pre-slice
//    per step instead of streaming a 128KB x-tile (the R8 critical-path cost). Lean scan kernel.
//  - else: R8 path verbatim (fused x, proven 5.9ms).

typedef _Float16 f16;
typedef _Float16 f16x8 __attribute__((ext_vector_type(8)));
typedef _Float16 f16x4 __attribute__((ext_vector_type(4)));
typedef float f32x4 __attribute__((ext_vector_type(4)));

static const size_t MB_ = 1024ull * 1024ull;
// ---- R8 (fallback) layout: needs 196MB ----
static const size_t OFF_X0    = 0;
static const size_t OFF_X1    = 64 * MB_;
static const size_t OFF_EMB   = OFF_X1;
static const size_t OFF_MLP1  = 96 * MB_;
static const size_t OFF_H     = 192 * MB_;
static const size_t OFF_FLAGS = 192 * MB_ + 512 * 1024;
static const size_t OFF_BIAS  = 192 * MB_ + 576 * 1024;
static const size_t OFF_W1C   = 193 * MB_;
static const size_t OFF_W2C   = 194 * MB_;
static const size_t WS_NEED   = 196 * MB_;
// ---- PRE layout: needs 272MB ----
// [0,128)=X1 (overlays X0[0,64) which dies after proj0); [128,256)=PRE (overlays EMB/MLP1 tmps,
// dead before proj0); smalls at [256,272).
static const size_t P_X0    = 0;
static const size_t P_X1    = 0;
static const size_t P_PRE   = 128 * MB_;
static const size_t P_EMB   = 128 * MB_;
static const size_t P_MLP1  = 160 * MB_;
static const size_t P_H     = 256 * MB_;
static const size_t P_FLAGS = 256 * MB_ + 512 * 1024;
static const size_t P_BIAS  = 256 * MB_ + 576 * 1024;
static const size_t P_W1C   = 257 * MB_;
static const size_t P_W2C   = 258 * MB_;
static const size_t P_WIH0C = 260 * MB_;  // [2][1024][1024] f16 = 4MB
static const size_t P_WIHLC = 264 * MB_;  // [2][1024][2048] f16 = 8MB
static const size_t WS_NEED2 = 272 * MB_;

__device__ __forceinline__ void gld16(const void* g, void* l) {
#if __has_builtin(__builtin_amdgcn_global_load_lds)
  __builtin_amdgcn_global_load_lds((const __attribute__((address_space(1))) void*)g,
                                   (__attribute__((address_space(3))) void*)l, 16, 0, 0);
#else
  *(f16x8*)l = *(const f16x8*)g;
#endif
}

// fast tanh: tanh(|x|) = 1 - 2/(exp2(2*log2e*|x|)+1); hw exp + rcp, abs err ~1e-6 << f16 rounding.
__device__ __forceinline__ float tanh_fast(float x) {
  float ax = __builtin_fabsf(x);
  float e = __builtin_amdgcn_exp2f(ax * 2.8853900817779268f);
  float r = 1.0f - 2.0f * __builtin_amdgcn_rcpf(e + 1.0f);
  return __builtin_copysignf(r, x);
}

// ---------------- utility kernels ----------------

__global__ void zero_k(unsigned int* __restrict__ p, int n) {
  int i = blockIdx.x * blockDim.x + threadIdx.x;
  if (i < n) p[i] = 0u;
}

__global__ void cvt_k(const float* __restrict__ in, f16* __restrict__ out, int n4) {
  int i = blockIdx.x * blockDim.x + threadIdx.x;
  int stride = gridDim.x * blockDim.x;
  for (; i < n4; i += stride) {
    float4 v = ((const float4*)in)[i];
    f16x4 o = {(f16)v.x, (f16)v.y, (f16)v.z, (f16)v.w};
    ((f16x4*)out)[i] = o;
  }
}

__global__ void bias_k(const float* __restrict__ a, const float* __restrict__ b, float* __restrict__ o) {
  int i = blockIdx.x * blockDim.x + threadIdx.x;
  if (i < 4096) o[i] = a[i] + b[i];
}

// embedding gather + f16 convert; padding_idx=0 -> zero row
__global__ void embed_k(const int* __restrict__ src, const float* __restrict__ tab, f16* __restrict__ out) {
  int m = blockIdx.x;
  int tid = threadIdx.x;
  int tok = src[m];
  f16x4 o = {(f16)0.f, (f16)0.f, (f16)0.f, (f16)0.f};
  if (tok != 0) {
    float4 v = *(const float4*)(tab + (size_t)tok * 512 + tid * 4);
    o[0] = (f16)v.x; o[1] = (f16)v.y; o[2] = (f16)v.z; o[3] = (f16)v.w;
  }
  *(f16x4*)(out + (size_t)m * 512 + tid * 4) = o;
}

// ---------------- GEMM: C[M,N] = A[M,K(lda)] * Bw[N,K]^T ----------------
// EPI bit0: relu(acc + bias[col]); EPI bit1: scatter row=(b*512+t) -> out[(t*64+b)*1024+col] (N==1024)
template <int EPI>
__global__ __launch_bounds__(256) void gemm_f16(
    const f16* __restrict__ A, int lda, const f16* __restrict__ Bw,
    f16* __restrict__ out, const float* __restrict__ bias, int M, int N, int K) {
  __shared__ alignas(16) f16 As[4096];
  __shared__ alignas(16) f16 Bs[4096];
  const int nt = N >> 7;
  const int bx = blockIdx.x;
  const int tm = bx / nt, tn = bx - tm * nt;
  const int tid = threadIdx.x;
  const int l = tid & 63, w = tid >> 6;
  const int wr = w >> 1, wc = w & 1;
  const int srow = (w << 4) + (l >> 2);
  const int scol = (l & 3) << 3;
  const f16* Ab = A + (size_t)(tm * 128 + srow) * lda + scol;
  const f16* Bb = Bw + (size_t)(tn * 128 + srow) * K + scol;
  f32x4 acc[4][4];
#pragma unroll
  for (int i = 0; i < 4; i++)
#pragma unroll
    for (int j = 0; j < 4; j++) acc[i][j] = (f32x4){0.f, 0.f, 0.f, 0.f};
  const int ar = l & 15, ak = (l >> 4) << 3;
  for (int k0 = 0; k0 < K; k0 += 32) {
    gld16(Ab + k0, &As[tid * 8]);
    gld16(Ab + (size_t)64 * lda + k0, &As[tid * 8 + 2048]);
    gld16(Bb + k0, &Bs[tid * 8]);
    gld16(Bb + (size_t)64 * K + k0, &Bs[tid * 8 + 2048]);
    __syncthreads();
    f16x8 av[4], bv[4];
#pragma unroll
    for (int i = 0; i < 4; i++) av[i] = *(const f16x8*)&As[(wr * 64 + i * 16 + ar) * 32 + ak];
#pragma unroll
    for (int j = 0; j < 4; j++) bv[j] = *(const f16x8*)&Bs[(wc * 64 + j * 16 + ar) * 32 + ak];
#pragma unroll
    for (int i = 0; i < 4; i++)
#pragma unroll
      for (int j = 0; j < 4; j++)
        acc[i][j] = __builtin_amdgcn_mfma_f32_16x16x32_f16(av[i], bv[j], acc[i][j], 0, 0, 0);
    __syncthreads();
  }
  const int r0 = (l >> 4) << 2, c0 = l & 15;
#pragma unroll
  for (int i = 0; i < 4; i++) {
#pragma unroll
    for (int j = 0; j < 4; j++) {
      const int col = tn * 128 + wc * 64 + j * 16 + c0;
      const float bc = (EPI & 1) ? bias[col] : 0.f;
#pragma unroll
      for (int r = 0; r < 4; r++) {
        const int row = tm * 128 + wr * 64 + i * 16 + r0 + r;
        float v = acc[i][j][r];
        if (EPI & 1) { v += bc; v = v > 0.f ? v : 0.f; }
        if (EPI & 2) {
          const int b_ = row >> 9, t = row & 511;
          out[((size_t)(t * 64 + b_) << 10) + col] = (f16)v;
        } else {
          out[(size_t)row * N + col] = (f16)v;
        }
      }
    }
  }
}

// ---------------- fused recurrence (R8, fallback path — unchanged) ----------------
template <int LAYER>
__global__ __launch_bounds__(512, 1) void rnn_scan(
    const f16* __restrict__ X, const float* __restrict__ Wih, const float* __restrict__ Whh,
    const float* __restrict__ bsum, f16* __restrict__ hbuf, unsigned int* __restrict__ flags,
    f16* __restrict__ seqout, float* __restrict__ dout) {
  constexpr int KX = LAYER ? 2048 : 1024;
  constexpr int XSH = LAYER ? 11 : 10;
  constexpr int NKX = KX / 128;
  constexpr int NKH = 8;
  const int bid = blockIdx.x;
  const int dir = bid >> 7, bg = (bid >> 6) & 1, cg = bid & 63;
  const int tid = threadIdx.x, l = tid & 63, w = tid >> 6;
  const int mi = w & 1, kq = w >> 1;
  __shared__ alignas(16) f16 Wl[16 * 1024];
  __shared__ alignas(16) f16 Wi[16 * KX];
  __shared__ f32x4 part[2][4][64];
  __shared__ alignas(16) f16 p2[32][16];
  __shared__ unsigned int cnt;
  const int ld = LAYER * 2 + dir;
  if (tid == 0) cnt = 0u;
  for (int ch = tid; ch < 2048; ch += 512) {
    const int n = ch >> 7, k0 = (ch & 127) << 3;
    const float* wp = Whh + (((size_t)(ld * 1024 + cg * 16 + n)) << 10) + k0;
    float4 v0 = *(const float4*)wp, v1 = *(const float4*)(wp + 4);
    f16x8 hv = {(f16)v0.x, (f16)v0.y, (f16)v0.z, (f16)v0.w,
                (f16)v1.x, (f16)v1.y, (f16)v1.z, (f16)v1.w};
    *(f16x8*)&Wl[(n << 10) + (k0 ^ ((n & 7) << 3))] = hv;
  }
  for (int ch = tid; ch < (16 * KX / 8); ch += 512) {
    const int n = ch >> (XSH - 3), k0 = (ch & (KX / 8 - 1)) << 3;
    const float* wp = Wih + ((size_t)(dir * 1024 + cg * 16 + n)) * KX + k0;
    float4 v0 = *(const float4*)wp, v1 = *(const float4*)(wp + 4);
    f16x8 hv = {(f16)v0.x, (f16)v0.y, (f16)v0.z, (f16)v0.w,
                (f16)v1.x, (f16)v1.y, (f16)v1.z, (f16)v1.w};
    *(f16x8*)&Wi[(n << XSH) + (k0 ^ ((n & 7) << 3))] = hv;
  }
  const float bn = bsum[(ld << 10) + cg * 16 + (l & 15)];
  f16* hD = hbuf + ((size_t)dir << 17);
  unsigned int* fl = flags + ((dir * 2 + bg) << 10);
  const int arow = bg * 32 + mi * 16 + (l & 15);
  const int akh = (kq << 8) + ((l >> 4) << 3);
  const int akx = kq * (KX / 4) + ((l >> 4) << 3);
  const int wn = l & 15;
  const int wsw = (wn & 7) << 3;

  f16x8 xv[NKX];
  {
    const int t0 = dir ? 511 : 0;
    const f16* xr = X + (((size_t)(t0 * 64 + arow)) << XSH) + akx;
#pragma unroll
    for (int i = 0; i < NKX; i++)
      asm volatile("global_load_dwordx4 %0, %1, off offset:%2"
                   : "=&v"(xv[i]) : "v"(xr), "i"(64 * i));
  }
  __syncthreads();

  for (int s = 0; s < 512; ++s) {
    const int t = dir ? (511 - s) : s;
    f32x4 acc = {0.f, 0.f, 0.f, 0.f};
    if (s > 0) {
      if (w == 7) {
        const unsigned int tgt = (unsigned int)(LAYER * 512 + s);
        unsigned int* fp = fl + l * 16;
        for (;;) {
          unsigned int f = __hip_atomic_load(fp, __ATOMIC_RELAXED, __HIP_MEMORY_SCOPE_AGENT);
          if (__all((int)(f >= tgt))) break;
        }
      }
      __syncthreads();
      const f16* hrow = hD + (((size_t)(s & 1)) << 16) + (((size_t)arow) << 10) + akh;
      f16x8 hv[NKH];
#pragma unroll
      for (int i = 0; i < NKH; i++)
        asm volatile("global_load_dwordx4 %0, %1, off offset:%2 sc0 sc1"
                     : "=&v"(hv[i]) : "v"(hrow), "i"(64 * i));
      asm volatile("s_waitcnt vmcnt(%0)" :: "i"(NKH) : "memory");
      __builtin_amdgcn_sched_barrier(0);
#pragma unroll
      for (int it = 0; it < NKX; ++it) {
        const int ko = akx + it * 32;
        f16x8 bv = *(const f16x8*)&Wi[(wn << XSH) + (ko ^ wsw)];
        acc = __builtin_amdgcn_mfma_f32_16x16x32_f16(xv[it], bv, acc, 0, 0, 0);
      }
      asm volatile("s_waitcnt vmcnt(0)" ::: "memory");
      __builtin_amdgcn_sched_barrier(0);
#pragma unroll
      for (int it = 0; it < NKH; ++it) {
        const int ko = akh + it * 32;
        f16x8 bv = *(const f16x8*)&Wl[(wn << 10) + (ko ^ wsw)];
        acc = __builtin_amdgcn_mfma_f32_16x16x32_f16(hv[it], bv, acc, 0, 0, 0);
      }
    } else {
      asm volatile("s_waitcnt vmcnt(0)" ::: "memory");
      __builtin_amdgcn_sched_barrier(0);
#pragma unroll
      for (int it = 0; it < NKX; ++it) {
        const int ko = akx + it * 32;
        f16x8 bv = *(const f16x8*)&Wi[(wn << XSH) + (ko ^ wsw)];
        acc = __builtin_amdgcn_mfma_f32_16x16x32_f16(xv[it], bv, acc, 0, 0, 0);
      }
    }
    part[mi][kq][l] = acc;
    __syncthreads();
    if (w < 2) {
      f32x4 sum = part[w][0][l];
      sum += part[w][1][l];
      sum += part[w][2][l];
      sum += part[w][3][l];
#pragma unroll
      for (int r = 0; r < 4; ++r) {
        const int row = ((l >> 4) << 2) + r;
        float v = tanh_fast(sum[r] + bn);
        p2[(w << 4) + row][l & 15] = (f16)v;
        if (s == 511) {
          const int b_ = bg * 32 + (w << 4) + row;
          dout[(((size_t)(ld * 64 + b_)) << 10) + cg * 16 + (l & 15)] = v;
        }
      }
      asm volatile("s_waitcnt lgkmcnt(0)" ::: "memory");
      __builtin_amdgcn_sched_barrier(0);
      if (l < 32) {
        const int rr = (w << 4) + (l >> 1), hf = l & 1;
        f16x8 pv = *(const f16x8*)&p2[rr][hf * 8];
        const int b_ = bg * 32 + rr;
        f16* hp = hD + (((size_t)((s + 1) & 1)) << 16) + (((size_t)b_) << 10) + cg * 16 + hf * 8;
        asm volatile("global_store_dwordx4 %0, %1, off sc0 sc1" :: "v"(hp), "v"(pv) : "memory");
        if (LAYER == 0) {
          f16* sp = seqout + (((size_t)(t * 64 + b_)) << 11) + (dir << 10) + cg * 16 + hf * 8;
          asm volatile("global_store_dwordx4 %0, %1, off" :: "v"(sp), "v"(pv) : "memory");
        }
      }
      asm volatile("s_waitcnt vmcnt(0)" ::: "memory");
      __builtin_amdgcn_sched_barrier(0);
      if (l == 0) {
        unsigned int old = __hip_atomic_fetch_add(&cnt, 1u, __ATOMIC_RELAXED,
                                                  __HIP_MEMORY_SCOPE_WORKGROUP);
        if (old == (unsigned int)(2 * s + 1))
          __hip_atomic_store(&fl[cg * 16], (unsigned int)(LAYER * 512 + s + 1),
                             __ATOMIC_RELAXED, __HIP_MEMORY_SCOPE_AGENT);
      }
    }
    if (s + 1 < 512) {
      const int tn_ = dir ? (511 - (s + 1)) : (s + 1);
      const f16* xr = X + (((size_t)(tn_ * 64 + arow)) << XSH) + akx;
#pragma unroll
      for (int i = 0; i < NKX; i++)
        asm volatile("global_load_dwordx4 %0, %1, off offset:%2"
                     : "=&v"(xv[i]) : "v"(xr), "i"(64 * i));
    }
  }
}

// ---------------- PRE-mode recurrence: x projection precomputed ----------------
// Identical sync/tail structure to R8 scan, but NO x loads / Wi LDS; reducers add a 2KB
// pre-slice (plain C++ loads, compiler-scoreboarded, prefetched one step ahead).
template <int LAYER>
__global__ __launch_bounds__(512, 1) void rnn_scan_pre(
    const f16* __restrict__ PRE,     // [2][512*64][1024], dir stride 1<<25 elems
    const float* __restrict__ Whh,
    const float* __restrict__ bsum,
    f16* __restrict__ hbuf,
    unsigned int* __restrict__ flags,
    f16* __restrict__ seqout,        // LAYER0: [512*64][2048]
    float* __restrict__ dout) {
  constexpr int NKH = 8;
  const int bid = blockIdx.x;
  const int dir = bid >> 7, bg = (bid >> 6) & 1, cg = bid & 63;
  const int tid = threadIdx.x, l = tid & 63, w = tid >> 6;
  const int mi = w & 1, kq = w >> 1;
  __shared__ alignas(16) f16 Wl[16 * 1024];
  __shared__ f32x4 part[2][4][64];
  __shared__ alignas(16) f16 p2[32][16];
  __shared__ unsigned int cnt;
  const int ld = LAYER * 2 + dir;
  if (tid == 0) cnt = 0u;
  for (int ch = tid; ch < 2048; ch += 512) {
    const int n = ch >> 7, k0 = (ch & 127) << 3;
    const float* wp = Whh + (((size_t)(ld * 1024 + cg * 16 + n)) << 10) + k0;
    float4 v0 = *(const float4*)wp, v1 = *(const float4*)(wp + 4);
    f16x8 hv = {(f16)v0.x, (f16)v0.y, (f16)v0.z, (f16)v0.w,
                (f16)v1.x, (f16)v1.y, (f16)v1.z, (f16)v1.w};
    *(f16x8*)&Wl[(n << 10) + (k0 ^ ((n & 7) << 3))] = hv;
  }
  const float bn = bsum[(ld << 10) + cg * 16 + (l & 15)];
  const f16* preD = PRE + (((size_t)dir) << 25);
  f16* hD = hbuf + ((size_t)dir << 17);
  unsigned int* fl = flags + ((dir * 2 + bg) << 10);
  const int arow = bg * 32 + mi * 16 + (l & 15);
  const int akh = (kq << 8) + ((l >> 4) << 3);
  const int wn = l & 15;
  const int wsw = (wn & 7) << 3;
  // reducer pre-slice base row: b0 = bg*32 + w*16 + (l>>4)*4, col cg*16 + (l&15)
  const int prow = bg * 32 + (w << 4) + ((l >> 4) << 2);
  const int pcol = cg * 16 + (l & 15);

  float pv0 = 0.f, pv1 = 0.f, pv2 = 0.f, pv3 = 0.f;
  if (w < 2) {  // prologue prefetch for s=0 (plain loads, compiler-managed)
    const int t0 = dir ? 511 : 0;
    const f16* pp = preD + (((size_t)(t0 * 64 + prow)) << 10) + pcol;
    pv0 = (float)pp[0]; pv1 = (float)pp[1 << 10];
    pv2 = (float)pp[2 << 10]; pv3 = (float)pp[3 << 10];
  }
  __syncthreads();

  for (int s = 0; s < 512; ++s) {
    const int t = dir ? (511 - s) : s;
    f32x4 acc = {0.f, 0.f, 0.f, 0.f};
    if (s > 0) {
      if (w == 7) {
        const unsigned int tgt = (unsigned int)(LAYER * 512 + s);
        unsigned int* fp = fl + l * 16;
        for (;;) {
          unsigned int f = __hip_atomic_load(fp, __ATOMIC_RELAXED, __HIP_MEMORY_SCOPE_AGENT);
          if (__all((int)(f >= tgt))) break;
        }
      }
      __syncthreads();
      const f16* hrow = hD + (((size_t)(s & 1)) << 16) + (((size_t)arow) << 10) + akh;
      f16x8 hv[NKH];
#pragma unroll
      for (int i = 0; i < NKH; i++)
        asm volatile("global_load_dwordx4 %0, %1, off offset:%2 sc0 sc1"
                     : "=&v"(hv[i]) : "v"(hrow), "i"(64 * i));
      asm volatile("s_waitcnt vmcnt(0)" ::: "memory");
      __builtin_amdgcn_sched_barrier(0);
#pragma unroll
      for (int it = 0; it < NKH; ++it) {
        const int ko = akh + it * 32;
        f16x8 bv = *(const f16x8*)&Wl[(wn << 10) + (ko ^ wsw)];
        acc = __builtin_amdgcn_mfma_f32_16x16x32_f16(hv[it], bv, acc, 0, 0, 0);
      }
    }
    part[mi][kq][l] = acc;
    __syncthreads();
    if (w < 2) {
      f32x4 sum = part[w][0][l];
      sum += part[w][1][l];
      sum += part[w][2][l];
      sum += part[w][3][l];
      float pva[4] = {pv0, pv1, pv2, pv3};
#pragma unroll
      for (int r = 0; r < 4; ++r) {
        const int row = ((l >> 4) << 2) + r;
        float v = tanh_fast(sum[r] + pva[r] + bn);
        p2[(w << 4) + row][l & 15] = (f16)v;
        if (s == 511) {
          const int b_ = bg * 32 + (w << 4) + row;
          dout[(((size_t)(ld * 64 + b_)) << 10) + cg * 16 + (l & 15)] = v;
        }
      }
      asm volatile("s_waitcnt lgkmcnt(0)" ::: "memory");
      __builtin_amdgcn_sched_barrier(0);
      if (l < 32) {
        const int rr = (w << 4) + (l >> 1), hf = l & 1;
        f16x8 pv = *(const f16x8*)&p2[rr][hf * 8];
        const int b_ = bg * 32 + rr;
        f16* hp = hD + (((size_t)((s + 1) & 1)) << 16) + (((size_t)b_) << 10) + cg * 16 + hf * 8;
        asm volatile("global_store_dwordx4 %0, %1, off sc0 sc1" :: "v"(hp), "v"(pv) : "memory");
        if (LAYER == 0) {
          f16* sp = seqout + (((size_t)(t * 64 + b_)) << 11) + (dir << 10) + cg * 16 + hf * 8;
          asm volatile("global_store_dwordx4 %0, %1, off" :: "v"(sp), "v"(pv) : "memory");
        }
      }
      asm volatile("s_waitcnt vmcnt(0)" ::: "memory");
      __builtin_amdgcn_sched_barrier(0);
      if (l == 0) {
        unsigned int old = __hip_atomic_fetch_add(&cnt, 1u, __ATOMIC_RELAXED,
                                                  __HIP_MEMORY_SCOPE_WORKGROUP);
        if (old == (unsigned int)(2 * s + 1))
          __hip_atomic_store(&fl[cg * 16], (unsigned int)(LAYER * 512 + s + 1),
                             __ATOMIC_RELAXED, __HIP_MEMORY_SCOPE_AGENT);
      }
      // prefetch pre for next step (plain loads; latency hides under next poll/h phase)
      if (s + 1 < 512) {
        const int tn_ = dir ? (511 - (s + 1)) : (s + 1);
        const f16* pp = preD + (((size_t)(tn_ * 64 + prow)) << 10) + pcol;
        pv0 = (float)pp[0]; pv1 = (float)pp[1 << 10];
        pv2 = (float)pp[2 << 10]; pv3 = (float)pp[3 << 10];
      }
    }
  }
}

// ---------------- launch ----------------

extern "C" void kernel_launch(void* const* d_in, const int* in_sizes, int n_in,
                              void* d_out, int out_size, void* d_ws, size_t ws_size,
                              hipStream_t stream) {
  const int* src    = (const int*)d_in[0];
  const float* emb  = (const float*)d_in[1];
  const float* W1   = (const float*)d_in[2];
  const float* b1   = (const float*)d_in[3];
  const float* W2   = (const float*)d_in[4];
  const float* b2   = (const float*)d_in[5];
  const float* Wih0 = (const float*)d_in[6];
  const float* WihL = (const float*)d_in[7];
  const float* Whh  = (const float*)d_in[8];
  const float* bih  = (const float*)d_in[9];
  const float* bhh  = (const float*)d_in[10];
  float* out = (float*)d_out;
  char* ws = (char*)d_ws;

  if (ws_size >= WS_NEED2) {
    // ---------------- PRE path ----------------
    f16* X0   = (f16*)(ws + P_X0);
    f16* X1   = (f16*)(ws + P_X1);
    f16* PRE  = (f16*)(ws + P_PRE);
    f16* EMB  = (f16*)(ws + P_EMB);
    f16* MLP1 = (f16*)(ws + P_MLP1);
    f16* HB   = (f16*)(ws + P_H);
    unsigned int* FLAGS = (unsigned int*)(ws + P_FLAGS);
    float* BIAS = (float*)(ws + P_BIAS);
    f16* W1C  = (f16*)(ws + P_W1C);
    f16* W2C  = (f16*)(ws + P_W2C);
    f16* WIH0C = (f16*)(ws + P_WIH0C);
    f16* WIHLC = (f16*)(ws + P_WIHLC);

    cvt_k<<<256, 256, 0, stream>>>(W1, W1C, 131072);
    cvt_k<<<256, 256, 0, stream>>>(W2, W2C, 262144);
    cvt_k<<<512, 256, 0, stream>>>(Wih0, WIH0C, 524288);
    cvt_k<<<512, 256, 0, stream>>>(WihL, WIHLC, 1048576);
    bias_k<<<16, 256, 0, stream>>>(bih, bhh, BIAS);
    zero_k<<<16, 256, 0, stream>>>(FLAGS, 4096);

    embed_k<<<32768, 128, 0, stream>>>(src, emb, EMB);
    gemm_f16<1><<<2048, 256, 0, stream>>>(EMB, 512, W1C, MLP1, b1, 32768, 1024, 512);
    gemm_f16<3><<<2048, 256, 0, stream>>>(MLP1, 1024, W2C, X0, b2, 32768, 1024, 1024);

    // layer-0 input projections (t-major A -> plain row-major store == [t][b][n])
    gemm_f16<0><<<2048, 256, 0, stream>>>(X0, 1024, WIH0C, PRE, nullptr, 32768, 1024, 1024);
    gemm_f16<0><<<2048, 256, 0, stream>>>(X0, 1024, WIH0C + (1u << 20), PRE + (1ull << 25),
                                          nullptr, 32768, 1024, 1024);
    rnn_scan_pre<0><<<256, 512, 0, stream>>>(PRE, Whh, BIAS, HB, FLAGS, X1, out);

    gemm_f16<0><<<2048, 256, 0, stream>>>(X1, 2048, WIHLC, PRE, nullptr, 32768, 1024, 2048);
    gemm_f16<0><<<2048, 256, 0, stream>>>(X1, 2048, WIHLC + (1u << 21), PRE + (1ull << 25),
                                          nullptr, 32768, 1024, 2048);
    rnn_scan_pre<1><<<256, 512, 0, stream>>>(PRE, Whh, BIAS, HB, FLAGS, nullptr, out);
    return;
  }

  if (ws_size < WS_NEED) {  // diagnostic fallback
    zero_k<<<(out_size + 255) / 256, 256, 0, stream>>>((unsigned int*)d_out, out_size);
    return;
  }

  // ---------------- R8 path (unchanged) ----------------
  f16* X0   = (f16*)(ws + OFF_X0);
  f16* X1   = (f16*)(ws + OFF_X1);
  f16* EMB  = (f16*)(ws + OFF_EMB);
  f16* MLP1 = (f16*)(ws + OFF_MLP1);
  f16* HB   = (f16*)(ws + OFF_H);
  unsigned int* FLAGS = (unsigned int*)(ws + OFF_FLAGS);
  float* BIAS = (float*)(ws + OFF_BIAS);
  f16* W1C  = (f16*)(ws + OFF_W1C);
  f16* W2C  = (f16*)(ws + OFF_W2C);

  cvt_k<<<256, 256, 0, stream>>>(W1, W1C, 131072);
  cvt_k<<<256, 256, 0, stream>>>(W2, W2C, 262144);
  bias_k<<<16, 256, 0, stream>>>(bih, bhh, BIAS);
  zero_k<<<16, 256, 0, stream>>>(FLAGS, 4096);

  embed_k<<<32768, 128, 0, stream>>>(src, emb, EMB);
  gemm_f16<1><<<2048, 256, 0, stream>>>(EMB, 512, W1C, MLP1, b1, 32768, 1024, 512);
  gemm_f16<3><<<2048, 256, 0, stream>>>(MLP1, 1024, W2C, X0, b2, 32768, 1024, 1024);

  rnn_scan<0><<<256, 512, 0, stream>>>(X0, Wih0, Whh, BIAS, HB, FLAGS, X1, out);
  rnn_scan<1><<<256, 512, 0, stream>>>(X1, WihL, Whh, BIAS, HB, FLAGS, nullptr, out);
}

// Round 14
// 5896.221 us; speedup vs baseline: 1.3206x; 1.0003x over previous
//
#include <hip/hip_runtime.h>

// RNNEncModel: embed -> MLP(relu x2) -> 2x bidirectional tanh-RNN -> final states [4,64,1024] f32.
// B=64 T=512 E=512 H=1024 V=32000.
// Round-14: R8-proven fused path + XCD-aware block-role swizzle. R8 counters showed the scans are
// HBM-bound on x re-fetch (3.1MB/step, 64 cg-blocks re-read the same 128KB slice; 4MB/XCD/step
// thrashes the 4MB L2). Swizzle maps each (dir,bg) sync group onto a dedicated XCD PAIR
// (xcd = blockIdx%8 round-robin) so co-XCD blocks share the x-slice in L2.
// PRE-projection branch abandoned (R10-R13: 4 failed bisections). ws NEED = 196MB.

typedef _Float16 f16;
typedef _Float16 f16x8 __attribute__((ext_vector_type(8)));
typedef _Float16 f16x4 __attribute__((ext_vector_type(4)));
typedef float f32x4 __attribute__((ext_vector_type(4)));

static const size_t MB_ = 1024ull * 1024ull;
static const size_t OFF_X0    = 0;
static const size_t OFF_X1    = 64 * MB_;
static const size_t OFF_EMB   = OFF_X1;
static const size_t OFF_MLP1  = 96 * MB_;
static const size_t OFF_H     = 192 * MB_;
static const size_t OFF_FLAGS = 192 * MB_ + 512 * 1024;
static const size_t OFF_BIAS  = 192 * MB_ + 576 * 1024;
static const size_t OFF_W1C   = 193 * MB_;
static const size_t OFF_W2C   = 194 * MB_;
static const size_t WS_NEED   = 196 * MB_;

__device__ __forceinline__ void gld16(const void* g, void* l) {
#if __has_builtin(__builtin_amdgcn_global_load_lds)
  __builtin_amdgcn_global_load_lds((const __attribute__((address_space(1))) void*)g,
                                   (__attribute__((address_space(3))) void*)l, 16, 0, 0);
#else
  *(f16x8*)l = *(const f16x8*)g;
#endif
}

// fast tanh: tanh(|x|) = 1 - 2/(exp2(2*log2e*|x|)+1); hw exp + rcp, abs err ~1e-6 << f16 rounding.
__device__ __forceinline__ float tanh_fast(float x) {
  float ax = __builtin_fabsf(x);
  float e = __builtin_amdgcn_exp2f(ax * 2.8853900817779268f);
  float r = 1.0f - 2.0f * __builtin_amdgcn_rcpf(e + 1.0f);
  return __builtin_copysignf(r, x);
}

// ---------------- utility kernels ----------------

__global__ void zero_k(unsigned int* __restrict__ p, int n) {
  int i = blockIdx.x * blockDim.x + threadIdx.x;
  if (i < n) p[i] = 0u;
}

__global__ void cvt_k(const float* __restrict__ in, f16* __restrict__ out, int n4) {
  int i = blockIdx.x * blockDim.x + threadIdx.x;
  int stride = gridDim.x * blockDim.x;
  for (; i < n4; i += stride) {
    float4 v = ((const float4*)in)[i];
    f16x4 o = {(f16)v.x, (f16)v.y, (f16)v.z, (f16)v.w};
    ((f16x4*)out)[i] = o;
  }
}

__global__ void bias_k(const float* __restrict__ a, const float* __restrict__ b, float* __restrict__ o) {
  int i = blockIdx.x * blockDim.x + threadIdx.x;
  if (i < 4096) o[i] = a[i] + b[i];
}

// embedding gather + f16 convert; padding_idx=0 -> zero row
__global__ void embed_k(const int* __restrict__ src, const float* __restrict__ tab, f16* __restrict__ out) {
  int m = blockIdx.x;
  int tid = threadIdx.x;
  int tok = src[m];
  f16x4 o = {(f16)0.f, (f16)0.f, (f16)0.f, (f16)0.f};
  if (tok != 0) {
    float4 v = *(const float4*)(tab + (size_t)tok * 512 + tid * 4);
    o[0] = (f16)v.x; o[1] = (f16)v.y; o[2] = (f16)v.z; o[3] = (f16)v.w;
  }
  *(f16x4*)(out + (size_t)m * 512 + tid * 4) = o;
}

// ---------------- GEMM: C[M,N] = A[M,K(lda)] * Bw[N,K]^T (B f16) ----------------
// EPI bit0: relu(acc + bias[col]); EPI bit1: scatter row=(b*512+t) -> out[(t*64+b)*1024+col]
template <int EPI>
__global__ __launch_bounds__(256) void gemm_f16(
    const f16* __restrict__ A, int lda, const f16* __restrict__ Bw,
    f16* __restrict__ out, const float* __restrict__ bias, int M, int N, int K) {
  __shared__ alignas(16) f16 As[4096];
  __shared__ alignas(16) f16 Bs[4096];
  const int nt = N >> 7;
  const int bx = blockIdx.x;
  const int tm = bx / nt, tn = bx - tm * nt;
  const int tid = threadIdx.x;
  const int l = tid & 63, w = tid >> 6;
  const int wr = w >> 1, wc = w & 1;
  const int srow = (w << 4) + (l >> 2);
  const int scol = (l & 3) << 3;
  const f16* Ab = A + (size_t)(tm * 128 + srow) * lda + scol;
  const f16* Bb = Bw + (size_t)(tn * 128 + srow) * K + scol;
  f32x4 acc[4][4];
#pragma unroll
  for (int i = 0; i < 4; i++)
#pragma unroll
    for (int j = 0; j < 4; j++) acc[i][j] = (f32x4){0.f, 0.f, 0.f, 0.f};
  const int ar = l & 15, ak = (l >> 4) << 3;
  for (int k0 = 0; k0 < K; k0 += 32) {
    gld16(Ab + k0, &As[tid * 8]);
    gld16(Ab + (size_t)64 * lda + k0, &As[tid * 8 + 2048]);
    gld16(Bb + k0, &Bs[tid * 8]);
    gld16(Bb + (size_t)64 * K + k0, &Bs[tid * 8 + 2048]);
    __syncthreads();
    f16x8 av[4], bv[4];
#pragma unroll
    for (int i = 0; i < 4; i++) av[i] = *(const f16x8*)&As[(wr * 64 + i * 16 + ar) * 32 + ak];
#pragma unroll
    for (int j = 0; j < 4; j++) bv[j] = *(const f16x8*)&Bs[(wc * 64 + j * 16 + ar) * 32 + ak];
#pragma unroll
    for (int i = 0; i < 4; i++)
#pragma unroll
      for (int j = 0; j < 4; j++)
        acc[i][j] = __builtin_amdgcn_mfma_f32_16x16x32_f16(av[i], bv[j], acc[i][j], 0, 0, 0);
    __syncthreads();
  }
  const int r0 = (l >> 4) << 2, c0 = l & 15;
#pragma unroll
  for (int i = 0; i < 4; i++) {
#pragma unroll
    for (int j = 0; j < 4; j++) {
      const int col = tn * 128 + wc * 64 + j * 16 + c0;
      const float bc = (EPI & 1) ? bias[col] : 0.f;
#pragma unroll
      for (int r = 0; r < 4; r++) {
        const int row = tm * 128 + wr * 64 + i * 16 + r0 + r;
        float v = acc[i][j][r];
        if (EPI & 1) { v += bc; v = v > 0.f ? v : 0.f; }
        if (EPI & 2) {
          const int b_ = row >> 9, t = row & 511;
          out[((size_t)(t * 64 + b_) << 10) + col] = (f16)v;
        } else {
          out[(size_t)row * N + col] = (f16)v;
        }
      }
    }
  }
}

// ---------------- fused recurrence (R8-proven; + XCD-aware role swizzle) ----------------
// Role swizzle: xcd = blockIdx%8 (HW round-robin). group g=(dir,bg) -> XCD pair {2g,2g+1}:
//   g = (bid&7)>>1 ; cg = (bid&1)*32 + (bid>>3).
// All 32 co-XCD blocks of a group read the SAME per-step x-slice -> L2-resident (was 4MB/XCD/step
// = thrash; now 128KB). Pure renaming of block roles; sync/dataflow identical to R8.
template <int LAYER>
__global__ __launch_bounds__(512, 1) void rnn_scan(
    const f16* __restrict__ X, const float* __restrict__ Wih, const float* __restrict__ Whh,
    const float* __restrict__ bsum, f16* __restrict__ hbuf, unsigned int* __restrict__ flags,
    f16* __restrict__ seqout, float* __restrict__ dout) {
  constexpr int KX = LAYER ? 2048 : 1024;
  constexpr int XSH = LAYER ? 11 : 10;
  constexpr int NKX = KX / 128;
  constexpr int NKH = 8;
  const int bid = blockIdx.x;
  const int g_ = (bid & 7) >> 1;
  const int dir = g_ >> 1, bg = g_ & 1;
  const int cg = ((bid & 1) << 5) | (bid >> 3);
  const int tid = threadIdx.x, l = tid & 63, w = tid >> 6;
  const int mi = w & 1, kq = w >> 1;
  __shared__ alignas(16) f16 Wl[16 * 1024];
  __shared__ alignas(16) f16 Wi[16 * KX];
  __shared__ f32x4 part[2][4][64];
  __shared__ alignas(16) f16 p2[32][16];
  __shared__ unsigned int cnt;
  const int ld = LAYER * 2 + dir;
  if (tid == 0) cnt = 0u;
  for (int ch = tid; ch < 2048; ch += 512) {
    const int n = ch >> 7, k0 = (ch & 127) << 3;
    const float* wp = Whh + (((size_t)(ld * 1024 + cg * 16 + n)) << 10) + k0;
    float4 v0 = *(const float4*)wp, v1 = *(const float4*)(wp + 4);
    f16x8 hv = {(f16)v0.x, (f16)v0.y, (f16)v0.z, (f16)v0.w,
                (f16)v1.x, (f16)v1.y, (f16)v1.z, (f16)v1.w};
    *(f16x8*)&Wl[(n << 10) + (k0 ^ ((n & 7) << 3))] = hv;
  }
  for (int ch = tid; ch < (16 * KX / 8); ch += 512) {
    const int n = ch >> (XSH - 3), k0 = (ch & (KX / 8 - 1)) << 3;
    const float* wp = Wih + ((size_t)(dir * 1024 + cg * 16 + n)) * KX + k0;
    float4 v0 = *(const float4*)wp, v1 = *(const float4*)(wp + 4);
    f16x8 hv = {(f16)v0.x, (f16)v0.y, (f16)v0.z, (f16)v0.w,
                (f16)v1.x, (f16)v1.y, (f16)v1.z, (f16)v1.w};
    *(f16x8*)&Wi[(n << XSH) + (k0 ^ ((n & 7) << 3))] = hv;
  }
  const float bn = bsum[(ld << 10) + cg * 16 + (l & 15)];
  f16* hD = hbuf + ((size_t)dir << 17);
  unsigned int* fl = flags + ((dir * 2 + bg) << 10);
  const int arow = bg * 32 + mi * 16 + (l & 15);
  const int akh = (kq << 8) + ((l >> 4) << 3);
  const int akx = kq * (KX / 4) + ((l >> 4) << 3);
  const int wn = l & 15;
  const int wsw = (wn & 7) << 3;

  f16x8 xv[NKX];
  {
    const int t0 = dir ? 511 : 0;
    const f16* xr = X + (((size_t)(t0 * 64 + arow)) << XSH) + akx;
#pragma unroll
    for (int i = 0; i < NKX; i++)
      asm volatile("global_load_dwordx4 %0, %1, off offset:%2"
                   : "=&v"(xv[i]) : "v"(xr), "i"(64 * i));
  }
  __syncthreads();

  for (int s = 0; s < 512; ++s) {
    const int t = dir ? (511 - s) : s;
    f32x4 acc = {0.f, 0.f, 0.f, 0.f};
    if (s > 0) {
      if (w == 7) {
        const unsigned int tgt = (unsigned int)(LAYER * 512 + s);
        unsigned int* fp = fl + l * 16;
        for (;;) {
          unsigned int f = __hip_atomic_load(fp, __ATOMIC_RELAXED, __HIP_MEMORY_SCOPE_AGENT);
          if (__all((int)(f >= tgt))) break;
        }
      }
      __syncthreads();
      const f16* hrow = hD + (((size_t)(s & 1)) << 16) + (((size_t)arow) << 10) + akh;
      f16x8 hv[NKH];
#pragma unroll
      for (int i = 0; i < NKH; i++)
        asm volatile("global_load_dwordx4 %0, %1, off offset:%2 sc0 sc1"
                     : "=&v"(hv[i]) : "v"(hrow), "i"(64 * i));
      asm volatile("s_waitcnt vmcnt(%0)" :: "i"(NKH) : "memory");
      __builtin_amdgcn_sched_barrier(0);
#pragma unroll
      for (int it = 0; it < NKX; ++it) {
        const int ko = akx + it * 32;
        f16x8 bv = *(const f16x8*)&Wi[(wn << XSH) + (ko ^ wsw)];
        acc = __builtin_amdgcn_mfma_f32_16x16x32_f16(xv[it], bv, acc, 0, 0, 0);
      }
      asm volatile("s_waitcnt vmcnt(0)" ::: "memory");
      __builtin_amdgcn_sched_barrier(0);
#pragma unroll
      for (int it = 0; it < NKH; ++it) {
        const int ko = akh + it * 32;
        f16x8 bv = *(const f16x8*)&Wl[(wn << 10) + (ko ^ wsw)];
        acc = __builtin_amdgcn_mfma_f32_16x16x32_f16(hv[it], bv, acc, 0, 0, 0);
      }
    } else {
      asm volatile("s_waitcnt vmcnt(0)" ::: "memory");
      __builtin_amdgcn_sched_barrier(0);
#pragma unroll
      for (int it = 0; it < NKX; ++it) {
        const int ko = akx + it * 32;
        f16x8 bv = *(const f16x8*)&Wi[(wn << XSH) + (ko ^ wsw)];
        acc = __builtin_amdgcn_mfma_f32_16x16x32_f16(xv[it], bv, acc, 0, 0, 0);
      }
    }
    part[mi][kq][l] = acc;
    __syncthreads();
    if (w < 2) {
      f32x4 sum = part[w][0][l];
      sum += part[w][1][l];
      sum += part[w][2][l];
      sum += part[w][3][l];
#pragma unroll
      for (int r = 0; r < 4; ++r) {
        const int row = ((l >> 4) << 2) + r;
        float v = tanh_fast(sum[r] + bn);
        p2[(w << 4) + row][l & 15] = (f16)v;
        if (s == 511) {
          const int b_ = bg * 32 + (w << 4) + row;
          dout[(((size_t)(ld * 64 + b_)) << 10) + cg * 16 + (l & 15)] = v;
        }
      }
      asm volatile("s_waitcnt lgkmcnt(0)" ::: "memory");
      __builtin_amdgcn_sched_barrier(0);
      if (l < 32) {
        const int rr = (w << 4) + (l >> 1), hf = l & 1;
        f16x8 pv = *(const f16x8*)&p2[rr][hf * 8];
        const int b_ = bg * 32 + rr;
        f16* hp = hD + (((size_t)((s + 1) & 1)) << 16) + (((size_t)b_) << 10) + cg * 16 + hf * 8;
        asm volatile("global_store_dwordx4 %0, %1, off sc0 sc1" :: "v"(hp), "v"(pv) : "memory");
        if (LAYER == 0) {
          f16* sp = seqout + (((size_t)(t * 64 + b_)) << 11) + (dir << 10) + cg * 16 + hf * 8;
          asm volatile("global_store_dwordx4 %0, %1, off" :: "v"(sp), "v"(pv) : "memory");
        }
      }
      asm volatile("s_waitcnt vmcnt(0)" ::: "memory");
      __builtin_amdgcn_sched_barrier(0);
      if (l == 0) {
        unsigned int old = __hip_atomic_fetch_add(&cnt, 1u, __ATOMIC_RELAXED,
                                                  __HIP_MEMORY_SCOPE_WORKGROUP);
        if (old == (unsigned int)(2 * s + 1))
          __hip_atomic_store(&fl[cg * 16], (unsigned int)(LAYER * 512 + s + 1),
                             __ATOMIC_RELAXED, __HIP_MEMORY_SCOPE_AGENT);
      }
    }
    if (s + 1 < 512) {
      const int tn_ = dir ? (511 - (s + 1)) : (s + 1);
      const f16* xr = X + (((size_t)(tn_ * 64 + arow)) << XSH) + akx;
#pragma unroll
      for (int i = 0; i < NKX; i++)
        asm volatile("global_load_dwordx4 %0, %1, off offset:%2"
                     : "=&v"(xv[i]) : "v"(xr), "i"(64 * i));
    }
  }
}

// ---------------- launch ----------------

extern "C" void kernel_launch(void* const* d_in, const int* in_sizes, int n_in,
                              void* d_out, int out_size, void* d_ws, size_t ws_size,
                              hipStream_t stream) {
  const int* src    = (const int*)d_in[0];
  const float* emb  = (const float*)d_in[1];
  const float* W1   = (const float*)d_in[2];
  const float* b1   = (const float*)d_in[3];
  const float* W2   = (const float*)d_in[4];
  const float* b2   = (const float*)d_in[5];
  const float* Wih0 = (const float*)d_in[6];
  const float* WihL = (const float*)d_in[7];
  const float* Whh  = (const float*)d_in[8];
  const float* bih  = (const float*)d_in[9];
  const float* bhh  = (const float*)d_in[10];
  float* out = (float*)d_out;
  char* ws = (char*)d_ws;

  if (ws_size < WS_NEED) {  // diagnostic fallback
    zero_k<<<(out_size + 255) / 256, 256, 0, stream>>>((unsigned int*)d_out, out_size);
    return;
  }

  f16* X0   = (f16*)(ws + OFF_X0);
  f16* X1   = (f16*)(ws + OFF_X1);
  f16* EMB  = (f16*)(ws + OFF_EMB);
  f16* MLP1 = (f16*)(ws + OFF_MLP1);
  f16* HB   = (f16*)(ws + OFF_H);
  unsigned int* FLAGS = (unsigned int*)(ws + OFF_FLAGS);
  float* BIAS = (float*)(ws + OFF_BIAS);
  f16* W1C  = (f16*)(ws + OFF_W1C);
  f16* W2C  = (f16*)(ws + OFF_W2C);

  cvt_k<<<256, 256, 0, stream>>>(W1, W1C, 131072);
  cvt_k<<<256, 256, 0, stream>>>(W2, W2C, 262144);
  bias_k<<<16, 256, 0, stream>>>(bih, bhh, BIAS);
  zero_k<<<16, 256, 0, stream>>>(FLAGS, 4096);

  embed_k<<<32768, 128, 0, stream>>>(src, emb, EMB);
  gemm_f16<1><<<2048, 256, 0, stream>>>(EMB, 512, W1C, MLP1, b1, 32768, 1024, 512);
  gemm_f16<3><<<2048, 256, 0, stream>>>(MLP1, 1024, W2C, X0, b2, 32768, 1024, 1024);

  rnn_scan<0><<<256, 512, 0, stream>>>(X0, Wih0, Whh, BIAS, HB, FLAGS, X1, out);
  rnn_scan<1><<<256, 512, 0, stream>>>(X1, WihL, Whh, BIAS, HB, FLAGS, nullptr, out);
}